// Round 1
// baseline (610.915 us; speedup 1.0000x reference)
//
#include <hip/hip_runtime.h>

#define L_DIM 4096
#define C_DIM 256
#define NB 4

typedef __bf16 bf16x8 __attribute__((ext_vector_type(8)));
typedef float f32x4 __attribute__((ext_vector_type(4)));

// ---------------- K0: zero the small workspace accumulators ----------------
__global__ void init_ws(float* __restrict__ rsum, float* __restrict__ csum,
                        unsigned int* __restrict__ colmax) {
    int i = blockIdx.x * 256 + threadIdx.x;
    if (i < NB * L_DIM) { rsum[i] = 0.f; csum[i] = 0.f; colmax[i] = 0u; }
}

// ---------------- K1: bf16 MFMA GEMM -> e = exp(sim) ----------------
// Tile 128x128, BK=64, 4 waves each computing 64x64 via 4x4 frags of 16x16x32.
// LDS rows padded 64->72 bf16 (144B) for uniform bank distribution.
__global__ __launch_bounds__(256) void gemm_exp(const float* __restrict__ f0,
                                                const float* __restrict__ f1,
                                                float* __restrict__ E) {
    const int n  = blockIdx.z;
    const int tl = blockIdx.y;
    const int ts = blockIdx.x;
    const float* A = f0 + ((size_t)n * L_DIM + (size_t)tl * 128) * C_DIM;
    const float* B = f1 + ((size_t)n * L_DIM + (size_t)ts * 128) * C_DIM;
    float* Eb = E + (size_t)n * L_DIM * L_DIM + (size_t)tl * 128 * L_DIM + (size_t)ts * 128;

    __shared__ __bf16 Al[128 * 72];
    __shared__ __bf16 Bl[128 * 72];

    const int t    = threadIdx.x;
    const int lane = t & 63;
    const int wave = t >> 6;
    const int wm   = wave >> 1, wn = wave & 1;
    const int q    = lane >> 4;
    const int l15  = lane & 15;

    f32x4 acc[4][4] = {};

    const int r8 = t >> 3;   // 0..31  (row group for staging)
    const int c8 = t & 7;    // 0..7   (8-float chunk within 64-col slab)

    for (int kt = 0; kt < C_DIM; kt += 64) {
        // ---- stage A,B slabs (128 rows x 64 k) f32 -> bf16 into LDS ----
        #pragma unroll
        for (int i = 0; i < 4; ++i) {
            int row = r8 + 32 * i;
            const float4* pa = (const float4*)(A + (size_t)row * C_DIM + kt + c8 * 8);
            float4 a0 = pa[0], a1 = pa[1];
            const float4* pb = (const float4*)(B + (size_t)row * C_DIM + kt + c8 * 8);
            float4 b0 = pb[0], b1 = pb[1];
            bf16x8 av, bv;
            av[0]=(__bf16)a0.x; av[1]=(__bf16)a0.y; av[2]=(__bf16)a0.z; av[3]=(__bf16)a0.w;
            av[4]=(__bf16)a1.x; av[5]=(__bf16)a1.y; av[6]=(__bf16)a1.z; av[7]=(__bf16)a1.w;
            bv[0]=(__bf16)b0.x; bv[1]=(__bf16)b0.y; bv[2]=(__bf16)b0.z; bv[3]=(__bf16)b0.w;
            bv[4]=(__bf16)b1.x; bv[5]=(__bf16)b1.y; bv[6]=(__bf16)b1.z; bv[7]=(__bf16)b1.w;
            *(bf16x8*)&Al[row * 72 + c8 * 8] = av;
            *(bf16x8*)&Bl[row * 72 + c8 * 8] = bv;
        }
        __syncthreads();
        // ---- MFMA over the two 32-wide k steps ----
        #pragma unroll
        for (int k2 = 0; k2 < 2; ++k2) {
            const int kk = k2 * 32 + q * 8;
            bf16x8 af[4], bfv[4];
            #pragma unroll
            for (int mf = 0; mf < 4; ++mf)
                af[mf] = *(const bf16x8*)&Al[(wm * 64 + mf * 16 + l15) * 72 + kk];
            #pragma unroll
            for (int nf = 0; nf < 4; ++nf)
                bfv[nf] = *(const bf16x8*)&Bl[(wn * 64 + nf * 16 + l15) * 72 + kk];
            #pragma unroll
            for (int mf = 0; mf < 4; ++mf)
                #pragma unroll
                for (int nf = 0; nf < 4; ++nf)
                    acc[mf][nf] = __builtin_amdgcn_mfma_f32_16x16x32_bf16(
                        af[mf], bfv[nf], acc[mf][nf], 0, 0, 0);
        }
        __syncthreads();
    }

    // ---- epilogue: e = exp(sim * scale);  scale = (1/256)/0.1 ----
    const float scale = 0.0390625f;
    #pragma unroll
    for (int mf = 0; mf < 4; ++mf) {
        #pragma unroll
        for (int nf = 0; nf < 4; ++nf) {
            int col = wn * 64 + nf * 16 + l15;
            #pragma unroll
            for (int reg = 0; reg < 4; ++reg) {
                int row = wm * 64 + mf * 16 + q * 4 + reg;  // C/D: col=lane&15, row=quad*4+reg
                Eb[(size_t)row * L_DIM + col] = __expf(acc[mf][nf][reg] * scale);
            }
        }
    }
}

// ---------------- K2: row sums (direct) + col sums (atomic) ----------------
__global__ __launch_bounds__(256) void sums_k(const float* __restrict__ E,
                                              float* __restrict__ rsum,
                                              float* __restrict__ csum) {
    const int n = blockIdx.y, strip = blockIdx.x;
    const float* Eb = E + (size_t)n * L_DIM * L_DIM + (size_t)strip * 64 * L_DIM;
    const int t = threadIdx.x, lane = t & 63, wave = t >> 6;
    __shared__ float redw[4][64];
    float colacc[16];
    #pragma unroll
    for (int k = 0; k < 16; ++k) colacc[k] = 0.f;
    for (int r = 0; r < 64; ++r) {
        const float* row = Eb + (size_t)r * L_DIM;
        float rs = 0.f;
        #pragma unroll
        for (int k = 0; k < 16; ++k) {
            float v = row[t + (k << 8)];
            rs += v; colacc[k] += v;
        }
        #pragma unroll
        for (int m = 1; m < 64; m <<= 1) rs += __shfl_xor(rs, m);
        if (lane == 0) redw[wave][r] = rs;
    }
    __syncthreads();
    if (t < 64)
        rsum[n * L_DIM + strip * 64 + t] = redw[0][t] + redw[1][t] + redw[2][t] + redw[3][t];
    #pragma unroll
    for (int k = 0; k < 16; ++k)
        atomicAdd(&csum[n * L_DIM + t + (k << 8)], colacc[k]);
}

// ---------------- K3: conf = e^2 * invr * invc (in place) + row/col max ----------------
__global__ __launch_bounds__(256) void conf_k(float* __restrict__ E,
                                              const float* __restrict__ rsum,
                                              const float* __restrict__ csum,
                                              unsigned long long* __restrict__ rowpack,
                                              unsigned int* __restrict__ colmax) {
    const int n = blockIdx.y, strip = blockIdx.x;
    float* Eb = E + (size_t)n * L_DIM * L_DIM + (size_t)strip * 64 * L_DIM;
    const int t = threadIdx.x, lane = t & 63, wave = t >> 6;
    __shared__ unsigned long long redw[4][64];
    float invc[16];
    #pragma unroll
    for (int k = 0; k < 16; ++k) invc[k] = 1.0f / csum[n * L_DIM + t + (k << 8)];
    unsigned int colbest[16];
    #pragma unroll
    for (int k = 0; k < 16; ++k) colbest[k] = 0u;

    for (int r = 0; r < 64; ++r) {
        float invr = 1.0f / rsum[n * L_DIM + strip * 64 + r];
        float* row = Eb + (size_t)r * L_DIM;
        unsigned long long best = 0ull;
        #pragma unroll
        for (int k = 0; k < 16; ++k) {
            int c = t + (k << 8);
            float e = row[c];
            float cf = e * e * invr * invc[k];
            row[c] = cf;
            unsigned int cb = __float_as_uint(cf);  // cf > 0 -> uint order == float order
            unsigned long long p = ((unsigned long long)cb << 32) | (unsigned int)(~c);
            best = p > best ? p : best;
            colbest[k] = cb > colbest[k] ? cb : colbest[k];
        }
        // wave max-reduce of packed (val, ~col)
        #pragma unroll
        for (int m = 1; m < 64; m <<= 1) {
            unsigned int hi = (unsigned int)(best >> 32), lo = (unsigned int)best;
            hi = __shfl_xor(hi, m); lo = __shfl_xor(lo, m);
            unsigned long long o = ((unsigned long long)hi << 32) | lo;
            best = o > best ? o : best;
        }
        if (lane == 0) redw[wave][r] = best;
    }
    __syncthreads();
    if (t < 64) {
        unsigned long long b = redw[0][t];
        b = redw[1][t] > b ? redw[1][t] : b;
        b = redw[2][t] > b ? redw[2][t] : b;
        b = redw[3][t] > b ? redw[3][t] : b;
        rowpack[n * L_DIM + strip * 64 + t] = b;   // block owns these rows fully
    }
    #pragma unroll
    for (int k = 0; k < 16; ++k)
        atomicMax(&colmax[n * L_DIM + t + (k << 8)], colbest[k]);
}

// ---------------- K4: matching outputs ----------------
__global__ void final_k(const unsigned long long* __restrict__ rowpack,
                        const unsigned int* __restrict__ colmax,
                        float* __restrict__ mask_out, float* __restrict__ j_out,
                        float* __restrict__ mconf_out) {
    int i = blockIdx.x * 256 + threadIdx.x;
    if (i >= NB * L_DIM) return;
    int n = i >> 12, l = i & 4095;
    unsigned long long rp = rowpack[i];
    float v = __uint_as_float((unsigned int)(rp >> 32));
    int s = (int)(~(unsigned int)(rp & 0xFFFFFFFFull));
    float cv = __uint_as_float(colmax[n * L_DIM + s]);
    int lh = l >> 6, lw = l & 63;
    int sh = s >> 6, sw = s & 63;
    bool bl = (lh >= 2) && (lh < 62) && (lw >= 2) && (lw < 62);
    bool bs = (sh >= 2) && (sh < 62) && (sw >= 2) && (sw < 62);
    bool m = (v > 0.2f) && bl && bs && (v == cv);
    mask_out[i]  = m ? 1.0f : 0.0f;
    j_out[i]     = m ? (float)s : 0.0f;
    mconf_out[i] = m ? v : 0.0f;
}

extern "C" void kernel_launch(void* const* d_in, const int* in_sizes, int n_in,
                              void* d_out, int out_size, void* d_ws, size_t ws_size,
                              hipStream_t stream) {
    const float* f0 = (const float*)d_in[0];
    const float* f1 = (const float*)d_in[1];

    float* out_conf  = (float*)d_out;                       // [4,4096,4096]
    float* out_mask  = out_conf + (size_t)NB * L_DIM * L_DIM;
    float* out_j     = out_mask + NB * L_DIM;
    float* out_mconf = out_j + NB * L_DIM;

    float* rsum = (float*)d_ws;                              //  64 KB
    float* csum = rsum + NB * L_DIM;                         //  64 KB
    unsigned int* colmax = (unsigned int*)(csum + NB * L_DIM);         // 64 KB
    unsigned long long* rowpack = (unsigned long long*)(colmax + NB * L_DIM); // 128 KB

    init_ws<<<dim3(64), dim3(256), 0, stream>>>(rsum, csum, colmax);
    gemm_exp<<<dim3(32, 32, NB), dim3(256), 0, stream>>>(f0, f1, out_conf);
    sums_k<<<dim3(64, NB), dim3(256), 0, stream>>>(out_conf, rsum, csum);
    conf_k<<<dim3(64, NB), dim3(256), 0, stream>>>(out_conf, rsum, csum, rowpack, colmax);
    final_k<<<dim3(64), dim3(256), 0, stream>>>(rowpack, colmax, out_mask, out_j, out_mconf);
}

// Round 2
// 531.407 us; speedup vs baseline: 1.1496x; 1.1496x over previous
//
#include <hip/hip_runtime.h>

#define L_DIM 4096
#define C_DIM 256
#define NB 4

typedef __bf16 bf16x8 __attribute__((ext_vector_type(8)));
typedef float f32x4 __attribute__((ext_vector_type(4)));

// ---------------- K0: zero the small workspace accumulators ----------------
__global__ void init_ws(float* __restrict__ rsum, float* __restrict__ csum,
                        unsigned int* __restrict__ colmax) {
    int i = blockIdx.x * 256 + threadIdx.x;
    if (i < NB * L_DIM) { rsum[i] = 0.f; csum[i] = 0.f; colmax[i] = 0u; }
}

// ---------------- K1: bf16 MFMA GEMM -> e = exp(sim), fused row/col sums ----
// Tile 128x128, BK=64, 4 waves each computing 64x64 via 4x4 frags of 16x16x32.
// Epilogue: e=exp(sim*scale) stored to E; row/col partial sums of e reduced
// in-wave (shuffles) and atomicAdd'ed to rsum/csum (removes the old K2 pass).
__global__ __launch_bounds__(256) void gemm_exp(const float* __restrict__ f0,
                                                const float* __restrict__ f1,
                                                float* __restrict__ E,
                                                float* __restrict__ rsum,
                                                float* __restrict__ csum) {
    const int n  = blockIdx.z;
    const int tl = blockIdx.y;
    const int ts = blockIdx.x;
    const float* A = f0 + ((size_t)n * L_DIM + (size_t)tl * 128) * C_DIM;
    const float* B = f1 + ((size_t)n * L_DIM + (size_t)ts * 128) * C_DIM;
    float* Eb = E + (size_t)n * L_DIM * L_DIM + (size_t)tl * 128 * L_DIM + (size_t)ts * 128;

    __shared__ __bf16 Al[128 * 72];
    __shared__ __bf16 Bl[128 * 72];

    const int t    = threadIdx.x;
    const int lane = t & 63;
    const int wave = t >> 6;
    const int wm   = wave >> 1, wn = wave & 1;
    const int q    = lane >> 4;
    const int l15  = lane & 15;

    f32x4 acc[4][4] = {};

    const int r8 = t >> 3;   // 0..31  (row group for staging)
    const int c8 = t & 7;    // 0..7   (8-float chunk within 64-col slab)

    for (int kt = 0; kt < C_DIM; kt += 64) {
        // ---- stage A,B slabs (128 rows x 64 k) f32 -> bf16 into LDS ----
        #pragma unroll
        for (int i = 0; i < 4; ++i) {
            int row = r8 + 32 * i;
            const float4* pa = (const float4*)(A + (size_t)row * C_DIM + kt + c8 * 8);
            float4 a0 = pa[0], a1 = pa[1];
            const float4* pb = (const float4*)(B + (size_t)row * C_DIM + kt + c8 * 8);
            float4 b0 = pb[0], b1 = pb[1];
            bf16x8 av, bv;
            av[0]=(__bf16)a0.x; av[1]=(__bf16)a0.y; av[2]=(__bf16)a0.z; av[3]=(__bf16)a0.w;
            av[4]=(__bf16)a1.x; av[5]=(__bf16)a1.y; av[6]=(__bf16)a1.z; av[7]=(__bf16)a1.w;
            bv[0]=(__bf16)b0.x; bv[1]=(__bf16)b0.y; bv[2]=(__bf16)b0.z; bv[3]=(__bf16)b0.w;
            bv[4]=(__bf16)b1.x; bv[5]=(__bf16)b1.y; bv[6]=(__bf16)b1.z; bv[7]=(__bf16)b1.w;
            *(bf16x8*)&Al[row * 72 + c8 * 8] = av;
            *(bf16x8*)&Bl[row * 72 + c8 * 8] = bv;
        }
        __syncthreads();
        // ---- MFMA over the two 32-wide k steps ----
        #pragma unroll
        for (int k2 = 0; k2 < 2; ++k2) {
            const int kk = k2 * 32 + q * 8;
            bf16x8 af[4], bfv[4];
            #pragma unroll
            for (int mf = 0; mf < 4; ++mf)
                af[mf] = *(const bf16x8*)&Al[(wm * 64 + mf * 16 + l15) * 72 + kk];
            #pragma unroll
            for (int nf = 0; nf < 4; ++nf)
                bfv[nf] = *(const bf16x8*)&Bl[(wn * 64 + nf * 16 + l15) * 72 + kk];
            #pragma unroll
            for (int mf = 0; mf < 4; ++mf)
                #pragma unroll
                for (int nf = 0; nf < 4; ++nf)
                    acc[mf][nf] = __builtin_amdgcn_mfma_f32_16x16x32_bf16(
                        af[mf], bfv[nf], acc[mf][nf], 0, 0, 0);
        }
        __syncthreads();
    }

    // ---- epilogue: e = exp(sim * scale);  scale = (1/256)/0.1 ----
    const float scale = 0.0390625f;
    #pragma unroll
    for (int mf = 0; mf < 4; ++mf)
        #pragma unroll
        for (int nf = 0; nf < 4; ++nf)
            #pragma unroll
            for (int reg = 0; reg < 4; ++reg)
                acc[mf][nf][reg] = __expf(acc[mf][nf][reg] * scale);

    // stores: C/D mapping col=lane&15 (+nf*16+wn*64), row=q*4+reg (+mf*16+wm*64)
    #pragma unroll
    for (int mf = 0; mf < 4; ++mf) {
        #pragma unroll
        for (int nf = 0; nf < 4; ++nf) {
            int col = wn * 64 + nf * 16 + l15;
            #pragma unroll
            for (int reg = 0; reg < 4; ++reg) {
                int row = wm * 64 + mf * 16 + q * 4 + reg;
                Eb[(size_t)row * L_DIM + col] = acc[mf][nf][reg];
            }
        }
    }

    // ---- fused row sums: sum over nf then over l15 (xor 1,2,4,8) ----
    {
        float rp[4][4];
        #pragma unroll
        for (int mf = 0; mf < 4; ++mf)
            #pragma unroll
            for (int reg = 0; reg < 4; ++reg) {
                float v = acc[mf][0][reg] + acc[mf][1][reg] + acc[mf][2][reg] + acc[mf][3][reg];
                v += __shfl_xor(v, 1); v += __shfl_xor(v, 2);
                v += __shfl_xor(v, 4); v += __shfl_xor(v, 8);
                rp[mf][reg] = v;
            }
        if (l15 == 0) {
            #pragma unroll
            for (int mf = 0; mf < 4; ++mf)
                #pragma unroll
                for (int reg = 0; reg < 4; ++reg)
                    atomicAdd(&rsum[n * L_DIM + tl * 128 + wm * 64 + mf * 16 + q * 4 + reg],
                              rp[mf][reg]);
        }
    }
    // ---- fused col sums: sum over mf,reg then over q (xor 16,32) ----
    {
        float cp[4];
        #pragma unroll
        for (int nf = 0; nf < 4; ++nf) {
            float v = 0.f;
            #pragma unroll
            for (int mf = 0; mf < 4; ++mf)
                #pragma unroll
                for (int reg = 0; reg < 4; ++reg)
                    v += acc[mf][nf][reg];
            v += __shfl_xor(v, 16); v += __shfl_xor(v, 32);
            cp[nf] = v;
        }
        if (q == 0) {
            #pragma unroll
            for (int nf = 0; nf < 4; ++nf)
                atomicAdd(&csum[n * L_DIM + ts * 128 + wn * 64 + nf * 16 + l15], cp[nf]);
        }
    }
}

// ---------------- K3: conf = e^2*invr*invc (in place) + row/col max ----------------
// 1024 threads (16 waves -> 4 waves/SIMD), thread owns 4 consecutive cols (float4).
__global__ __launch_bounds__(1024) void conf_k(float* __restrict__ E,
                                               const float* __restrict__ rsum,
                                               const float* __restrict__ csum,
                                               unsigned long long* __restrict__ rowpack,
                                               unsigned int* __restrict__ colmax) {
    const int n = blockIdx.y, strip = blockIdx.x;
    float* Eb = E + (size_t)n * L_DIM * L_DIM + (size_t)strip * 64 * L_DIM;
    const int t = threadIdx.x, lane = t & 63, wave = t >> 6;
    __shared__ unsigned long long redw[64][16];

    f32x4 invc;
    {
        f32x4 cs = *(const f32x4*)&csum[n * L_DIM + t * 4];
        invc[0] = 1.0f / cs[0]; invc[1] = 1.0f / cs[1];
        invc[2] = 1.0f / cs[2]; invc[3] = 1.0f / cs[3];
    }
    unsigned int colbest[4] = {0u, 0u, 0u, 0u};
    const unsigned int notc0 = ~(unsigned int)(t * 4);

    for (int r = 0; r < 64; ++r) {
        float invr = 1.0f / rsum[n * L_DIM + strip * 64 + r];
        float* row = Eb + (size_t)r * L_DIM;
        f32x4 e = *(f32x4*)&row[t * 4];
        f32x4 cf;
        #pragma unroll
        for (int j = 0; j < 4; ++j) cf[j] = e[j] * e[j] * invr * invc[j];
        *(f32x4*)&row[t * 4] = cf;

        unsigned long long best = 0ull;
        #pragma unroll
        for (int j = 0; j < 4; ++j) {
            unsigned int cb = __float_as_uint(cf[j]);   // cf>0: uint order == float order
            unsigned long long p = ((unsigned long long)cb << 32) | (notc0 - j);
            best = p > best ? p : best;
            colbest[j] = cb > colbest[j] ? cb : colbest[j];
        }
        #pragma unroll
        for (int m = 1; m < 64; m <<= 1) {
            unsigned int hi = (unsigned int)(best >> 32), lo = (unsigned int)best;
            hi = __shfl_xor(hi, m); lo = __shfl_xor(lo, m);
            unsigned long long o = ((unsigned long long)hi << 32) | lo;
            best = o > best ? o : best;
        }
        if (lane == 0) redw[r][wave] = best;
    }
    __syncthreads();
    if (t < 64) {
        unsigned long long b = 0ull;
        #pragma unroll
        for (int w = 0; w < 16; ++w) {
            unsigned long long v = redw[t][w];
            b = v > b ? v : b;
        }
        rowpack[n * L_DIM + strip * 64 + t] = b;   // block owns these rows fully
    }
    #pragma unroll
    for (int j = 0; j < 4; ++j)
        atomicMax(&colmax[n * L_DIM + t * 4 + j], colbest[j]);
}

// ---------------- K4: matching outputs ----------------
__global__ void final_k(const unsigned long long* __restrict__ rowpack,
                        const unsigned int* __restrict__ colmax,
                        float* __restrict__ mask_out, float* __restrict__ j_out,
                        float* __restrict__ mconf_out) {
    int i = blockIdx.x * 256 + threadIdx.x;
    if (i >= NB * L_DIM) return;
    int n = i >> 12, l = i & 4095;
    unsigned long long rp = rowpack[i];
    float v = __uint_as_float((unsigned int)(rp >> 32));
    int s = (int)(~(unsigned int)(rp & 0xFFFFFFFFull));
    float cv = __uint_as_float(colmax[n * L_DIM + s]);
    int lh = l >> 6, lw = l & 63;
    int sh = s >> 6, sw = s & 63;
    bool bl = (lh >= 2) && (lh < 62) && (lw >= 2) && (lw < 62);
    bool bs = (sh >= 2) && (sh < 62) && (sw >= 2) && (sw < 62);
    bool m = (v > 0.2f) && bl && bs && (v == cv);
    mask_out[i]  = m ? 1.0f : 0.0f;
    j_out[i]     = m ? (float)s : 0.0f;
    mconf_out[i] = m ? v : 0.0f;
}

extern "C" void kernel_launch(void* const* d_in, const int* in_sizes, int n_in,
                              void* d_out, int out_size, void* d_ws, size_t ws_size,
                              hipStream_t stream) {
    const float* f0 = (const float*)d_in[0];
    const float* f1 = (const float*)d_in[1];

    float* out_conf  = (float*)d_out;                       // [4,4096,4096]
    float* out_mask  = out_conf + (size_t)NB * L_DIM * L_DIM;
    float* out_j     = out_mask + NB * L_DIM;
    float* out_mconf = out_j + NB * L_DIM;

    float* rsum = (float*)d_ws;                              //  64 KB
    float* csum = rsum + NB * L_DIM;                         //  64 KB
    unsigned int* colmax = (unsigned int*)(csum + NB * L_DIM);         // 64 KB
    unsigned long long* rowpack = (unsigned long long*)(colmax + NB * L_DIM); // 128 KB

    init_ws<<<dim3(64), dim3(256), 0, stream>>>(rsum, csum, colmax);
    gemm_exp<<<dim3(32, 32, NB), dim3(256), 0, stream>>>(f0, f1, out_conf, rsum, csum);
    conf_k<<<dim3(64, NB), dim3(1024), 0, stream>>>(out_conf, rsum, csum, rowpack, colmax);
    final_k<<<dim3(64), dim3(256), 0, stream>>>(rowpack, colmax, out_mask, out_j, out_mconf);
}